// Round 1
// baseline (44.232 us; speedup 1.0000x reference)
//
#include <hip/hip_runtime.h>
#include <math.h>

#define B_ 512
#define I_ 512
#define O_ 512
#define TB 64
#define TO 16
#define KI 16
#define NCH (I_/KI)            // 32 chunks
#define LXS (TB + 4)           // 68: keeps 16B alignment for float4 reads, breaks bank stride

#define K_EXP  (-0.72134752044448170f)   // -0.5 * log2(e)
#define NORM_  (0.86732507058407750f)    // 2 / (sqrt(3) * pi^0.25)
#define BN_EPS (1e-5f)

#if defined(__has_builtin)
#if __has_builtin(__builtin_amdgcn_exp2f)
#define EXP2F(v) __builtin_amdgcn_exp2f(v)
#endif
#endif
#ifndef EXP2F
#define EXP2F(v) exp2f(v)
#endif

// Kernel 1: y[b,o] = NORM * sum_i (t2-1)*exp(-t2/2)*w,  t = (x-bias)/scale.
// Also emits per-(b-tile, o) partial sum and sum-of-squares for the batchnorm.
__global__ __launch_bounds__(256) void kan_main(
    const float* __restrict__ x, const float* __restrict__ scale,
    const float* __restrict__ bias, const float* __restrict__ weight,
    float* __restrict__ y, float* __restrict__ psum, float* __restrict__ psumsq)
{
    __shared__ float Lx[KI][LXS];      // x transposed: [i_local][b_local]
    __shared__ float Lp[KI][TO][4];    // {rs, bias*rs, w, pad}
    __shared__ float Rs[2][TB/4][TO];  // stats reduction scratch

    const int t   = threadIdx.x;
    const int to  = t & (TO - 1);      // o within tile
    const int tb4 = t >> 4;            // 0..15, owns b_local = tb4*4 .. +3
    const int o0  = blockIdx.x * TO;
    const int b0  = blockIdx.y * TB;

    // loader mappings
    const int lb = t >> 2;             // 0..63 : b row for x staging
    const int lq = t & 3;              // i-quarter for x staging
    const int li = t >> 4;             // 0..15 : i row for param staging
    const int lo = t & 15;             // o col for param staging

    float acc0 = 0.f, acc1 = 0.f, acc2 = 0.f, acc3 = 0.f;

    for (int ch = 0; ch < NCH; ++ch) {
        const int i0 = ch * KI;
        // issue global loads before the barrier so they overlap the barrier wait
        const float4 xv = *reinterpret_cast<const float4*>(&x[(b0 + lb) * I_ + i0 + lq * 4]);
        const int pidx = (i0 + li) * O_ + o0 + lo;
        const float sc = scale[pidx];
        const float bi = bias[pidx];
        const float w  = weight[pidx];

        __syncthreads();               // previous chunk fully consumed

        Lx[lq * 4 + 0][lb] = xv.x;
        Lx[lq * 4 + 1][lb] = xv.y;
        Lx[lq * 4 + 2][lb] = xv.z;
        Lx[lq * 4 + 3][lb] = xv.w;
        const float rs = __builtin_amdgcn_rcpf(sc);
        Lp[li][lo][0] = rs;
        Lp[li][lo][1] = bi * rs;
        Lp[li][lo][2] = w;

        __syncthreads();               // staging visible

        #pragma unroll
        for (int ii = 0; ii < KI; ++ii) {
            const float4 p  = *reinterpret_cast<const float4*>(&Lp[ii][to][0]);
            const float4 xx = *reinterpret_cast<const float4*>(&Lx[ii][tb4 * 4]);
            // 5 VALU + 1 exp per eval
            {
                const float tt = fmaf(xx.x, p.x, -p.y);
                const float t2 = tt * tt;
                const float e  = EXP2F(t2 * K_EXP);
                const float g  = fmaf(t2, p.z, -p.z);
                acc0 = fmaf(g, e, acc0);
            }
            {
                const float tt = fmaf(xx.y, p.x, -p.y);
                const float t2 = tt * tt;
                const float e  = EXP2F(t2 * K_EXP);
                const float g  = fmaf(t2, p.z, -p.z);
                acc1 = fmaf(g, e, acc1);
            }
            {
                const float tt = fmaf(xx.z, p.x, -p.y);
                const float t2 = tt * tt;
                const float e  = EXP2F(t2 * K_EXP);
                const float g  = fmaf(t2, p.z, -p.z);
                acc2 = fmaf(g, e, acc2);
            }
            {
                const float tt = fmaf(xx.w, p.x, -p.y);
                const float t2 = tt * tt;
                const float e  = EXP2F(t2 * K_EXP);
                const float g  = fmaf(t2, p.z, -p.z);
                acc3 = fmaf(g, e, acc3);
            }
        }
    }

    const float y0 = NORM_ * acc0;
    const float y1 = NORM_ * acc1;
    const float y2 = NORM_ * acc2;
    const float y3 = NORM_ * acc3;

    const int brow = b0 + tb4 * 4;
    y[(brow + 0) * O_ + o0 + to] = y0;
    y[(brow + 1) * O_ + o0 + to] = y1;
    y[(brow + 2) * O_ + o0 + to] = y2;
    y[(brow + 3) * O_ + o0 + to] = y3;

    // per-block column partials for BN
    Rs[0][tb4][to] = y0 + y1 + y2 + y3;
    Rs[1][tb4][to] = y0 * y0 + y1 * y1 + y2 * y2 + y3 * y3;
    __syncthreads();
    if (t < TO) {
        float s = 0.f, s2 = 0.f;
        #pragma unroll
        for (int k = 0; k < TB / 4; ++k) {
            s  += Rs[0][k][t];
            s2 += Rs[1][k][t];
        }
        psum  [blockIdx.y * O_ + o0 + t] = s;
        psumsq[blockIdx.y * O_ + o0 + t] = s2;
    }
}

// Kernel 2: combine partials -> mean/var per column, normalize d_out in place.
__global__ __launch_bounds__(256) void bn_apply(
    const float* __restrict__ psum, const float* __restrict__ psumsq,
    const float* __restrict__ gamma, const float* __restrict__ beta,
    float* __restrict__ y)
{
    const int o = blockIdx.x * 256 + threadIdx.x;
    float s = 0.f, s2 = 0.f;
    #pragma unroll
    for (int k = 0; k < B_ / TB; ++k) {
        s  += psum  [k * O_ + o];
        s2 += psumsq[k * O_ + o];
    }
    const float mean = s * (1.0f / B_);
    const float var  = s2 * (1.0f / B_) - mean * mean;
    const float inv  = rsqrtf(var + BN_EPS);
    const float a = gamma[o] * inv;
    const float c = fmaf(-mean, a, beta[o]);

    const int bstart = blockIdx.y * 16;
    #pragma unroll
    for (int b = bstart; b < bstart + 16; ++b) {
        const int idx = b * O_ + o;
        y[idx] = fmaf(y[idx], a, c);
    }
}

extern "C" void kernel_launch(void* const* d_in, const int* in_sizes, int n_in,
                              void* d_out, int out_size, void* d_ws, size_t ws_size,
                              hipStream_t stream) {
    const float* x      = (const float*)d_in[0];
    const float* scale  = (const float*)d_in[1];
    const float* bias   = (const float*)d_in[2];
    const float* weight = (const float*)d_in[3];
    const float* gamma  = (const float*)d_in[4];
    const float* beta   = (const float*)d_in[5];
    float* out = (float*)d_out;

    float* psum   = (float*)d_ws;            // (B/TB=8) x O
    float* psumsq = psum + (B_ / TB) * O_;   // 16 KB + 16 KB of ws

    dim3 g1(O_ / TO, B_ / TB);               // (32, 8) = 256 blocks
    kan_main<<<g1, 256, 0, stream>>>(x, scale, bias, weight, out, psum, psumsq);

    dim3 g2(O_ / 256, B_ / 16);              // (2, 32) = 64 blocks
    bn_apply<<<g2, 256, 0, stream>>>(psum, psumsq, gamma, beta, out);
}